// Round 1
// baseline (859.107 us; speedup 1.0000x reference)
//
#include <hip/hip_runtime.h>
#include <math.h>

// Problem constants
#define BCH  8     // batch
#define INC  32    // in channels
#define OUTC 32    // out channels
#define NSZ  256   // spatial N
#define DD   64    // D1 = D2
#define BW   5     // window
#define TT   68    // D + BW - 1

// ---------------------------------------------------------------------------
// Build orthonormal DST-I matrix (symmetric, involutory), fp64 math for the
// angle to stay well inside the harness threshold.
// ---------------------------------------------------------------------------
__global__ void build_dst(float* __restrict__ Mmat) {
    int idx = blockIdx.x * blockDim.x + threadIdx.x;
    if (idx >= NSZ * NSZ) return;
    int i = idx >> 8, j = idx & 255;
    double arg = M_PI * (double)((i + 1) * (j + 1)) / 257.0;
    Mmat[idx] = (float)(sqrt(2.0 / 257.0) * sin(arg));
}

// ---------------------------------------------------------------------------
// Generic batched SGEMM (NN): C[m,n] = sum_k A[m,k] * B[k,n]
// BM=BN=64, BK=16, 256 threads, 4x4 micro-tile per thread.
// K must be a multiple of 16. Row-major with arbitrary leading dims and
// per-batch strides (stride 0 = shared operand).
// ---------------------------------------------------------------------------
__global__ __launch_bounds__(256) void gemm_nn(
    const float* __restrict__ A, const float* __restrict__ B, float* __restrict__ C,
    int M, int N, int K, int lda, int ldb, int ldc,
    long long sA, long long sB, long long sC)
{
    const int batch = blockIdx.z;
    A += (long long)batch * sA;
    B += (long long)batch * sB;
    C += (long long)batch * sC;
    const int mt = blockIdx.y * 64;
    const int nt = blockIdx.x * 64;

    __shared__ float As[16][68];   // transposed: As[k][m], row 68 floats (16B-aligned rows)
    __shared__ float Bs[16][68];   // Bs[k][n]

    const int tid = threadIdx.x;
    const int tx = tid & 15;       // n micro index
    const int ty = tid >> 4;       // m micro index

    // load-phase indices
    const int ar = tid >> 2;         // 0..63 : A tile row
    const int ac = (tid & 3) * 4;    // 0,4,8,12 : A tile col (k)
    const int br = tid >> 4;         // 0..15 : B tile row (k)
    const int bc = (tid & 15) * 4;   // 0..60 : B tile col

    float acc[4][4] = {};

    for (int k0 = 0; k0 < K; k0 += 16) {
        // ---- stage A tile (transposed into LDS) ----
        float4 av = make_float4(0.f, 0.f, 0.f, 0.f);
        if (mt + ar < M)
            av = *(const float4*)&A[(long long)(mt + ar) * lda + (k0 + ac)];
        As[ac + 0][ar] = av.x;
        As[ac + 1][ar] = av.y;
        As[ac + 2][ar] = av.z;
        As[ac + 3][ar] = av.w;

        // ---- stage B tile ----
        if (nt + bc + 3 < N) {
            float4 bv = *(const float4*)&B[(long long)(k0 + br) * ldb + (nt + bc)];
            Bs[br][bc + 0] = bv.x;
            Bs[br][bc + 1] = bv.y;
            Bs[br][bc + 2] = bv.z;
            Bs[br][bc + 3] = bv.w;
        } else {
            #pragma unroll
            for (int t = 0; t < 4; ++t)
                Bs[br][bc + t] = (nt + bc + t < N)
                               ? B[(long long)(k0 + br) * ldb + (nt + bc + t)] : 0.f;
        }
        __syncthreads();

        // ---- compute ----
        #pragma unroll
        for (int kk = 0; kk < 16; ++kk) {
            float4 a4 = *(const float4*)&As[kk][ty * 4];
            float4 b4 = *(const float4*)&Bs[kk][tx * 4];
            float a_[4] = {a4.x, a4.y, a4.z, a4.w};
            float b_[4] = {b4.x, b4.y, b4.z, b4.w};
            #pragma unroll
            for (int i = 0; i < 4; ++i)
                #pragma unroll
                for (int j = 0; j < 4; ++j)
                    acc[i][j] += a_[i] * b_[j];
        }
        __syncthreads();
    }

    // ---- epilogue ----
    #pragma unroll
    for (int i = 0; i < 4; ++i) {
        int row = mt + ty * 4 + i;
        if (row < M) {
            #pragma unroll
            for (int j = 0; j < 4; ++j) {
                int col = nt + tx * 4 + j;
                if (col < N)
                    C[(long long)row * ldc + col] = acc[i][j];
            }
        }
    }
}

// ---------------------------------------------------------------------------
// K4: per-spectral-mode windowed contraction.
//   y[b,o,d1,d2] = sum_{c,i,j} at[b,c,d1+i,d2+j] * W[(c*25+i*5+j), o, d1*64+d2]
// Block = (d1, o-group of 4). 256 threads: tx=d2 (0..63), ty=o-sub (0..3).
// Weights streamed coalesced, each element read exactly once device-wide.
// at rows staged in LDS per c.
// ---------------------------------------------------------------------------
__global__ __launch_bounds__(256) void spectral_conv(
    const float* __restrict__ at, const float* __restrict__ W, float* __restrict__ y)
{
    const int d1  = blockIdx.x;       // 0..63
    const int og  = blockIdx.y;       // 0..7
    const int tid = threadIdx.x;
    const int d2  = tid & 63;
    const int oty = tid >> 6;         // 0..3
    const int o   = og * 4 + oty;
    const int x   = d1 * 64 + d2;

    __shared__ float ats[BCH][BW][TT];   // 8*5*68*4 = 10880 B

    float acc[BCH] = {};

    for (int c = 0; c < INC; ++c) {
        __syncthreads();
        for (int idx = tid; idx < BCH * BW * TT; idx += 256) {
            int b = idx / (BW * TT);
            int r = idx % (BW * TT);
            int i = r / TT;
            int q = r % TT;
            ats[b][i][q] = at[((b * INC + c) * TT + (d1 + i)) * TT + q];
        }
        __syncthreads();

        #pragma unroll
        for (int i = 0; i < BW; ++i) {
            #pragma unroll
            for (int j = 0; j < BW; ++j) {
                float w = W[(((c * 25 + i * 5 + j) * OUTC + o) << 12) + x];
                #pragma unroll
                for (int b = 0; b < BCH; ++b)
                    acc[b] += ats[b][i][d2 + j] * w;
            }
        }
    }

    #pragma unroll
    for (int b = 0; b < BCH; ++b)
        y[((b * OUTC + o) << 12) + x] = acc[b];
}

// ---------------------------------------------------------------------------
// Launch
// ---------------------------------------------------------------------------
extern "C" void kernel_launch(void* const* d_in, const int* in_sizes, int n_in,
                              void* d_out, int out_size, void* d_ws, size_t ws_size,
                              hipStream_t stream) {
    const float* u = (const float*)d_in[0];   // (8,32,256,256)
    const float* W = (const float*)d_in[1];   // (800,32,4096)
    float* out = (float*)d_out;               // (8,32,256,256)

    float* ws = (float*)d_ws;
    float* Mm = ws;                            // 65536 floats
    float* t1 = Mm + NSZ * NSZ;                // 256 * 68*256 = 4,456,448 floats
    float* atb = t1 + 256 * (TT * NSZ);        // 256 * 68*68  = 1,183,744 floats
    float* yb  = atb + 256 * (TT * TT);        // 256 * 4096   = 1,048,576 floats
    float* sb  = t1;                           // alias: t1 dead after S2; s = 256*16384 fits

    // Build DST matrix
    build_dst<<<dim3((NSZ * NSZ + 255) / 256), dim3(256), 0, stream>>>(Mm);

    // S1: t1[bc,p,y] = sum_x M[p,x] * u[bc,x,y]   (M symmetric), p<68
    gemm_nn<<<dim3(4, 2, 256), dim3(256), 0, stream>>>(
        Mm, u, t1, TT, NSZ, NSZ, NSZ, NSZ, NSZ,
        0LL, (long long)NSZ * NSZ, (long long)TT * NSZ);

    // S2: at[bc,p,q] = sum_y t1[bc,p,y] * M[y,q], q<68
    gemm_nn<<<dim3(2, 2, 256), dim3(256), 0, stream>>>(
        t1, Mm, atb, TT, TT, NSZ, NSZ, NSZ, TT,
        (long long)TT * NSZ, 0LL, (long long)TT * TT);

    // K4: per-mode weighted contraction -> yb (8,32,64,64)
    spectral_conv<<<dim3(64, 8), dim3(256), 0, stream>>>(atb, W, yb);

    // S4: s[bo,d1,m2] = sum_d2 yb[bo,d1,d2] * M[d2,m2]
    gemm_nn<<<dim3(4, 1, 256), dim3(256), 0, stream>>>(
        yb, Mm, sb, DD, NSZ, DD, DD, NSZ, NSZ,
        (long long)DD * DD, 0LL, (long long)DD * NSZ);

    // S5: out[bo,m1,m2] = sum_d1 M[m1,d1] * s[bo,d1,m2]
    gemm_nn<<<dim3(4, 4, 256), dim3(256), 0, stream>>>(
        Mm, sb, out, NSZ, NSZ, DD, NSZ, NSZ, NSZ,
        0LL, (long long)DD * NSZ, (long long)NSZ * NSZ);
}

// Round 2
// 728.387 us; speedup vs baseline: 1.1795x; 1.1795x over previous
//
#include <hip/hip_runtime.h>
#include <math.h>

// Problem constants
#define BCH  8     // batch
#define INC  32    // in channels
#define OUTC 32    // out channels
#define NSZ  256   // spatial N
#define DD   64    // D1 = D2
#define BW   5     // window
#define TT   68    // D + BW - 1
#define CCH  8     // c-chunks in spectral conv
#define CPC  4     // channels per chunk (INC/CCH)

// ---------------------------------------------------------------------------
// Orthonormal DST-I matrix (symmetric, involutory), fp64 angles.
// ---------------------------------------------------------------------------
__global__ void build_dst(float* __restrict__ Mmat) {
    int idx = blockIdx.x * blockDim.x + threadIdx.x;
    if (idx >= NSZ * NSZ) return;
    int i = idx >> 8, j = idx & 255;
    double arg = M_PI * (double)((i + 1) * (j + 1)) / 257.0;
    Mmat[idx] = (float)(sqrt(2.0 / 257.0) * sin(arg));
}

// ---------------------------------------------------------------------------
// Generic batched SGEMM (NN), 64x64 tile, 4x4 micro. For the small stages.
// ---------------------------------------------------------------------------
__global__ __launch_bounds__(256) void gemm_nn(
    const float* __restrict__ A, const float* __restrict__ B, float* __restrict__ C,
    int M, int N, int K, int lda, int ldb, int ldc,
    long long sA, long long sB, long long sC)
{
    const int batch = blockIdx.z;
    A += (long long)batch * sA;
    B += (long long)batch * sB;
    C += (long long)batch * sC;
    const int mt = blockIdx.y * 64;
    const int nt = blockIdx.x * 64;

    __shared__ float As[16][68];
    __shared__ float Bs[16][68];

    const int tid = threadIdx.x;
    const int tx = tid & 15;
    const int ty = tid >> 4;
    const int ar = tid >> 2;
    const int ac = (tid & 3) * 4;
    const int br = tid >> 4;
    const int bc = (tid & 15) * 4;

    float acc[4][4] = {};

    for (int k0 = 0; k0 < K; k0 += 16) {
        float4 av = make_float4(0.f, 0.f, 0.f, 0.f);
        if (mt + ar < M)
            av = *(const float4*)&A[(long long)(mt + ar) * lda + (k0 + ac)];
        As[ac + 0][ar] = av.x;
        As[ac + 1][ar] = av.y;
        As[ac + 2][ar] = av.z;
        As[ac + 3][ar] = av.w;

        if (nt + bc + 3 < N) {
            float4 bv = *(const float4*)&B[(long long)(k0 + br) * ldb + (nt + bc)];
            Bs[br][bc + 0] = bv.x;
            Bs[br][bc + 1] = bv.y;
            Bs[br][bc + 2] = bv.z;
            Bs[br][bc + 3] = bv.w;
        } else {
            #pragma unroll
            for (int t = 0; t < 4; ++t)
                Bs[br][bc + t] = (nt + bc + t < N)
                               ? B[(long long)(k0 + br) * ldb + (nt + bc + t)] : 0.f;
        }
        __syncthreads();

        #pragma unroll
        for (int kk = 0; kk < 16; ++kk) {
            float4 a4 = *(const float4*)&As[kk][ty * 4];
            float4 b4 = *(const float4*)&Bs[kk][tx * 4];
            float a_[4] = {a4.x, a4.y, a4.z, a4.w};
            float b_[4] = {b4.x, b4.y, b4.z, b4.w};
            #pragma unroll
            for (int i = 0; i < 4; ++i)
                #pragma unroll
                for (int j = 0; j < 4; ++j)
                    acc[i][j] += a_[i] * b_[j];
        }
        __syncthreads();
    }

    #pragma unroll
    for (int i = 0; i < 4; ++i) {
        int row = mt + ty * 4 + i;
        if (row < M) {
            #pragma unroll
            for (int j = 0; j < 4; ++j) {
                int col = nt + tx * 4 + j;
                if (col < N)
                    C[(long long)row * ldc + col] = acc[i][j];
            }
        }
    }
}

// ---------------------------------------------------------------------------
// gemm128: 128x128 tile, 8x8 micro-tile, 256 threads, BK=16.
// ASSUMES: A physically has >= mt+128 rows and >= K cols (stages unguarded),
//          B physically has full K x (nt+128). C stores guarded by M.
// True for S1 (A = M 256x256) and S5 (A = M, K=64).
// ---------------------------------------------------------------------------
__global__ __launch_bounds__(256) void gemm128(
    const float* __restrict__ A, const float* __restrict__ B, float* __restrict__ C,
    int Mstore, int K, int lda, int ldb, int ldc,
    long long sA, long long sB, long long sC)
{
    const int batch = blockIdx.z;
    A += (long long)batch * sA;
    B += (long long)batch * sB;
    C += (long long)batch * sC;
    const int mt = blockIdx.y * 128;
    const int nt = blockIdx.x * 128;

    __shared__ float As[16][128];   // As[k][m]
    __shared__ float Bs[16][128];   // Bs[k][n]

    const int tid = threadIdx.x;
    const int tx = tid & 15;        // n: n0 = tx*8
    const int ty = tid >> 4;        // m: m0 = ty*8
    const int n0 = tx * 8;
    const int m0 = ty * 8;

    float acc[8][8] = {};

    for (int k0 = 0; k0 < K; k0 += 16) {
        // stage A: 128 rows x 16 cols = 512 float4; 2 per thread, transposed
        #pragma unroll
        for (int t = 0; t < 2; ++t) {
            int idx = tid * 2 + t;
            int r = idx >> 2;          // 0..127 tile row
            int q = idx & 3;           // float4 within the 16-col strip
            float4 av = *(const float4*)&A[(long long)(mt + r) * lda + (k0 + q * 4)];
            As[q * 4 + 0][r] = av.x;
            As[q * 4 + 1][r] = av.y;
            As[q * 4 + 2][r] = av.z;
            As[q * 4 + 3][r] = av.w;
        }
        // stage B: 16 rows x 128 cols = 512 float4; 2 per thread
        #pragma unroll
        for (int t = 0; t < 2; ++t) {
            int idx = tid * 2 + t;
            int r = idx >> 5;          // 0..15 k row
            int q = idx & 31;          // float4 within 128 cols
            float4 bv = *(const float4*)&B[(long long)(k0 + r) * ldb + (nt + q * 4)];
            *(float4*)&Bs[r][q * 4] = bv;
        }
        __syncthreads();

        #pragma unroll
        for (int kk = 0; kk < 16; ++kk) {
            float4 a0 = *(const float4*)&As[kk][m0];
            float4 a1 = *(const float4*)&As[kk][m0 + 4];
            float4 b0 = *(const float4*)&Bs[kk][n0];
            float4 b1 = *(const float4*)&Bs[kk][n0 + 4];
            float a_[8] = {a0.x, a0.y, a0.z, a0.w, a1.x, a1.y, a1.z, a1.w};
            float b_[8] = {b0.x, b0.y, b0.z, b0.w, b1.x, b1.y, b1.z, b1.w};
            #pragma unroll
            for (int i = 0; i < 8; ++i)
                #pragma unroll
                for (int j = 0; j < 8; ++j)
                    acc[i][j] += a_[i] * b_[j];
        }
        __syncthreads();
    }

    #pragma unroll
    for (int i = 0; i < 8; ++i) {
        int row = mt + m0 + i;
        if (row < Mstore) {
            float4 c0 = make_float4(acc[i][0], acc[i][1], acc[i][2], acc[i][3]);
            float4 c1 = make_float4(acc[i][4], acc[i][5], acc[i][6], acc[i][7]);
            *(float4*)&C[(long long)row * ldc + nt + n0]     = c0;
            *(float4*)&C[(long long)row * ldc + nt + n0 + 4] = c1;
        }
    }
}

// ---------------------------------------------------------------------------
// spectral_conv2: y_p[cc][b,o,d1,d2] = sum_{c in chunk,i,j} at[b,c,d1+i,d2+j]
//                                      * W[(c*25+i*5+j), o, d1*64+d2]
// grid (64 d1, 8 cc), block 256: tx = tid&7 (d2 octet, d2 = tx*8..tx*8+7),
// o = tid>>3 (0..31). Weights: float4 loads, each element read once
// device-wide. acc[8 batch][8 d2] in registers.
// ---------------------------------------------------------------------------
__global__ __launch_bounds__(256, 2) void spectral_conv2(
    const float* __restrict__ at, const float* __restrict__ W, float* __restrict__ yp)
{
    const int d1  = blockIdx.x;
    const int cc  = blockIdx.y;
    const int tid = threadIdx.x;
    const int tx  = tid & 7;
    const int o   = tid >> 3;
    const int xb  = d1 * 64 + tx * 8;

    __shared__ float ats[BCH * BW * TT];   // [b*5+i][68] rows, 272B each

    float acc[BCH][8] = {};

    for (int cl = 0; cl < CPC; ++cl) {
        const int c = cc * CPC + cl;
        __syncthreads();
        // stage: 40 rows (b,i) x 68 floats = 680 float4
        for (int idx = tid; idx < 680; idx += 256) {
            int r  = idx / 17;          // b*5 + i
            int q4 = idx % 17;
            int b  = r / 5;
            int i  = r % 5;
            float4 v = *(const float4*)&at[(((b * INC + c) * TT) + d1 + i) * TT + q4 * 4];
            *(float4*)&ats[r * TT + q4 * 4] = v;
        }
        __syncthreads();

        #pragma unroll
        for (int i = 0; i < BW; ++i) {
            // 10 float4 weight loads for this (c,i): j=0..4, halves
            float wj[BW][8];
            #pragma unroll
            for (int j = 0; j < BW; ++j) {
                const float* wp = &W[(((long long)(c * 25 + i * 5 + j) * OUTC + o) << 12) + xb];
                float4 w0 = *(const float4*)&wp[0];
                float4 w1 = *(const float4*)&wp[4];
                wj[j][0] = w0.x; wj[j][1] = w0.y; wj[j][2] = w0.z; wj[j][3] = w0.w;
                wj[j][4] = w1.x; wj[j][5] = w1.y; wj[j][6] = w1.z; wj[j][7] = w1.w;
            }
            #pragma unroll
            for (int b = 0; b < BCH; ++b) {
                const float* ar = &ats[(b * BW + i) * TT + tx * 8];
                float4 a0 = *(const float4*)&ar[0];
                float4 a1 = *(const float4*)&ar[4];
                float4 a2 = *(const float4*)&ar[8];
                float av[12] = {a0.x, a0.y, a0.z, a0.w,
                                a1.x, a1.y, a1.z, a1.w,
                                a2.x, a2.y, a2.z, a2.w};
                #pragma unroll
                for (int j = 0; j < BW; ++j)
                    #pragma unroll
                    for (int k = 0; k < 8; ++k)
                        acc[b][k] += av[j + k] * wj[j][k];
            }
        }
    }

    float* yo = yp + (long long)cc * (BCH * OUTC * 4096);
    #pragma unroll
    for (int b = 0; b < BCH; ++b) {
        float4 c0 = make_float4(acc[b][0], acc[b][1], acc[b][2], acc[b][3]);
        float4 c1 = make_float4(acc[b][4], acc[b][5], acc[b][6], acc[b][7]);
        float* p = &yo[((b * OUTC + o) << 12) + xb];
        *(float4*)&p[0] = c0;
        *(float4*)&p[4] = c1;
    }
}

// ---------------------------------------------------------------------------
// reduce 8 partials -> yb
// ---------------------------------------------------------------------------
__global__ __launch_bounds__(256) void reduce8(
    const float* __restrict__ yp, float* __restrict__ yb)
{
    int idx = blockIdx.x * blockDim.x + threadIdx.x;   // float4 index, < 262144
    float4 s = make_float4(0.f, 0.f, 0.f, 0.f);
    #pragma unroll
    for (int p = 0; p < CCH; ++p) {
        float4 v = *(const float4*)&yp[(long long)p * (BCH * OUTC * 4096) + idx * 4];
        s.x += v.x; s.y += v.y; s.z += v.z; s.w += v.w;
    }
    *(float4*)&yb[idx * 4] = s;
}

// ---------------------------------------------------------------------------
// Launch
// ---------------------------------------------------------------------------
extern "C" void kernel_launch(void* const* d_in, const int* in_sizes, int n_in,
                              void* d_out, int out_size, void* d_ws, size_t ws_size,
                              hipStream_t stream) {
    const float* u = (const float*)d_in[0];   // (8,32,256,256)
    const float* W = (const float*)d_in[1];   // (800,32,4096)
    float* out = (float*)d_out;               // (8,32,256,256)

    float* ws = (float*)d_ws;
    float* Mm = ws;                            // 65,536
    float* t1 = Mm + NSZ * NSZ;                // 256*68*256 = 4,456,448
    float* atb = t1 + 256 * (TT * NSZ);        // 256*68*68  = 1,183,744
    float* yb  = atb + 256 * (TT * TT);        // 8*32*4096  = 1,048,576
    float* ypart = yb + BCH * OUTC * 4096;     // 8 * 1,048,576
    float* sb  = t1;                           // alias: t1 dead after S2

    build_dst<<<dim3((NSZ * NSZ + 255) / 256), dim3(256), 0, stream>>>(Mm);

    // S1: t1[bc,p,y] = sum_x M[p,x] u[bc,x,y], p<68  (M=68 pad 128, N=256, K=256)
    gemm128<<<dim3(2, 1, 256), dim3(256), 0, stream>>>(
        Mm, u, t1, TT, NSZ, NSZ, NSZ, NSZ,
        0LL, (long long)NSZ * NSZ, (long long)TT * NSZ);

    // S2: at[bc,p,q] = sum_y t1[bc,p,y] M[y,q], q<68
    gemm_nn<<<dim3(2, 2, 256), dim3(256), 0, stream>>>(
        t1, Mm, atb, TT, TT, NSZ, NSZ, NSZ, TT,
        (long long)TT * NSZ, 0LL, (long long)TT * TT);

    // K4: split-c spectral conv -> 8 partials, then reduce
    spectral_conv2<<<dim3(64, CCH), dim3(256), 0, stream>>>(atb, W, ypart);
    reduce8<<<dim3(1024), dim3(256), 0, stream>>>(ypart, yb);

    // S4: s[bo,d1,m2] = sum_d2 yb[bo,d1,d2] M[d2,m2]   (M=64, N=256, K=64)
    gemm_nn<<<dim3(4, 1, 256), dim3(256), 0, stream>>>(
        yb, Mm, sb, DD, NSZ, DD, DD, NSZ, NSZ,
        (long long)DD * DD, 0LL, (long long)DD * NSZ);

    // S5: out[bo,m1,m2] = sum_d1 M[m1,d1] s[bo,d1,m2]  (M=256, N=256, K=64)
    gemm128<<<dim3(2, 2, 256), dim3(256), 0, stream>>>(
        Mm, sb, out, NSZ, DD, NSZ, NSZ, NSZ,
        0LL, (long long)DD * NSZ, (long long)NSZ * NSZ);
}